// Round 1
// baseline (225.457 us; speedup 1.0000x reference)
//
#include <hip/hip_runtime.h>
#include <math.h>

#define DDIM 4096
#define EXPERTS 64
#define TT 64        // tokens per block
#define KT 64        // k per tile
#define NTILES (DDIM / KT)

// ---- async global->LDS, 16B per lane, wave-uniform LDS base ----
__device__ __forceinline__ void gload_lds16(const void* g, void* l) {
  __builtin_amdgcn_global_load_lds(
      (const __attribute__((address_space(1))) void*)g,
      (__attribute__((address_space(3))) void*)l,
      16, 0, 0);
}

// stage one 64x64 fp32 tile of x (row-quad XOR-swizzled source) and one
// 64x64 tile of wT (linear) into LDS. 32 chunks of 1KiB, 8 per wave.
__device__ __forceinline__ void stage_tile(const float* __restrict__ gx,
                                           const float* __restrict__ gw,
                                           float* xsn, float* wsn,
                                           int lane, int wv) {
#pragma unroll
  for (int j = 0; j < 4; ++j) {
    const int c = wv * 4 + j;
    const int row = 4 * c + (lane >> 4);
    const int col4 = (lane & 15) ^ (c & 3);            // pre-swizzled source
    gload_lds16(gx + (size_t)row * DDIM + (col4 << 2), xsn + c * 256);
    gload_lds16(gw + c * 256 + (lane << 2),            wsn + c * 256);
  }
}

// 4k x (4 experts) FMA micro-tile: p.{x,y,z,w} = experts e0..e0+3
__device__ __forceinline__ void fma44(const float4 a, const float4 w0,
                                      const float4 w1, const float4 w2,
                                      const float4 w3, float4& p) {
  p.x = fmaf(a.x, w0.x, p.x); p.x = fmaf(a.y, w1.x, p.x);
  p.x = fmaf(a.z, w2.x, p.x); p.x = fmaf(a.w, w3.x, p.x);
  p.y = fmaf(a.x, w0.y, p.y); p.y = fmaf(a.y, w1.y, p.y);
  p.y = fmaf(a.z, w2.y, p.y); p.y = fmaf(a.w, w3.y, p.y);
  p.z = fmaf(a.x, w0.z, p.z); p.z = fmaf(a.y, w1.z, p.z);
  p.z = fmaf(a.z, w2.z, p.z); p.z = fmaf(a.w, w3.z, p.z);
  p.w = fmaf(a.x, w0.w, p.w); p.w = fmaf(a.y, w1.w, p.w);
  p.w = fmaf(a.z, w2.w, p.w); p.w = fmaf(a.w, w3.w, p.w);
}

__global__ __launch_bounds__(256, 1) void moe_gate_main(
    const float* __restrict__ x,    // [N][4096]
    const float* __restrict__ wT,   // [4096][64]
    float* __restrict__ out,        // idx [N*8], w [N*8], aux
    float* __restrict__ pi_g,       // [64]
    float* __restrict__ ce_g,       // [64]
    int N) {
  __shared__ float smem[16384];     // 64 KiB: xs0,xs1,ws0,ws1 (4x4096)
  float* lt = smem;                 // reused: logits [64 experts][stride 68]
  float* inv_s = smem + 8192;       // reused ws0 region after GEMM
  float* ce_lds = smem + 8256;

  const int tid = threadIdx.x;
  const int lane = tid & 63;
  const int wv = tid >> 6;          // wave 0..3
  const int te = tid & 15;          // expert group -> e0 = 4*te
  const int tt = tid >> 4;          // token group  -> t0 = 4*tt
  const int token0 = blockIdx.x * TT;
  const int swz = tt & 3;
  const int ebase = te << 2;

  float4 acc[4];
#pragma unroll
  for (int t = 0; t < 4; ++t) acc[t] = make_float4(0.f, 0.f, 0.f, 0.f);

  const float* gx0 = x + (size_t)token0 * DDIM;

  // prologue: stage tile 0 into buffer 0
  stage_tile(gx0, wT, smem, smem + 8192, lane, wv);
  asm volatile("s_waitcnt vmcnt(0)" ::: "memory");
  __syncthreads();

#pragma unroll 1
  for (int kt = 0; kt < NTILES; ++kt) {
    const int cur = kt & 1;
    if (kt + 1 < NTILES) {
      stage_tile(gx0 + (kt + 1) * KT, wT + (size_t)(kt + 1) * KT * EXPERTS,
                 smem + ((kt + 1) & 1) * 4096,
                 smem + 8192 + ((kt + 1) & 1) * 4096, lane, wv);
    }
    const float* xb = smem + cur * 4096;
    const float* wb = smem + 8192 + cur * 4096;

    float4 part[4];
#pragma unroll
    for (int t = 0; t < 4; ++t) part[t] = make_float4(0.f, 0.f, 0.f, 0.f);

#pragma unroll
    for (int kc = 0; kc < KT; kc += 4) {
      const int cq = (((kc >> 2) ^ swz) << 2);
      float4 xv0 = *(const float4*)(xb + ((tt << 2) + 0) * 64 + cq);
      float4 xv1 = *(const float4*)(xb + ((tt << 2) + 1) * 64 + cq);
      float4 xv2 = *(const float4*)(xb + ((tt << 2) + 2) * 64 + cq);
      float4 xv3 = *(const float4*)(xb + ((tt << 2) + 3) * 64 + cq);
      float4 w0 = *(const float4*)(wb + (kc + 0) * 64 + ebase);
      float4 w1 = *(const float4*)(wb + (kc + 1) * 64 + ebase);
      float4 w2 = *(const float4*)(wb + (kc + 2) * 64 + ebase);
      float4 w3 = *(const float4*)(wb + (kc + 3) * 64 + ebase);
      fma44(xv0, w0, w1, w2, w3, part[0]);
      fma44(xv1, w0, w1, w2, w3, part[1]);
      fma44(xv2, w0, w1, w2, w3, part[2]);
      fma44(xv3, w0, w1, w2, w3, part[3]);
    }
#pragma unroll
    for (int t = 0; t < 4; ++t) {
      acc[t].x += part[t].x; acc[t].y += part[t].y;
      acc[t].z += part[t].z; acc[t].w += part[t].w;
    }
    asm volatile("s_waitcnt vmcnt(0)" ::: "memory");
    __syncthreads();
  }

  // ---- epilogue: logits -> LDS as lt[expert][token], stride 68 ----
  const int trow = tt << 2;
#pragma unroll
  for (int t = 0; t < 4; ++t) {
    float av[4] = {acc[t].x, acc[t].y, acc[t].z, acc[t].w};
#pragma unroll
    for (int e = 0; e < 4; ++e) lt[(ebase + e) * 68 + trow + t] = av[e];
  }
  __syncthreads();

  const int sl = lane & 15;
  const bool act = (lane < 16);
  const int tokS = (wv << 4) + sl;   // token (phase S/T) / expert (phase P) id

  // phase S: softmax per token (store p = exp(l - m) back into lt)
  float inv = 0.f;
  if (act) {
    ce_lds[tokS] = 0.0f;
    float m = -1e30f;
    for (int e = 0; e < 64; ++e) m = fmaxf(m, lt[e * 68 + tokS]);
    float s = 0.f;
    for (int e = 0; e < 64; ++e) {
      float p = expf(lt[e * 68 + tokS] - m);
      lt[e * 68 + tokS] = p;
      s += p;
    }
    inv = 1.0f / s;
    inv_s[tokS] = inv;
  }
  __syncthreads();

  // phase P: per-expert partial of pi = sum_tokens score
  if (act) {
    const int e = tokS;
    float s = 0.f;
    for (int tok = 0; tok < 64; ++tok) s += lt[e * 68 + tok] * inv_s[tok];
    atomicAdd(pi_g + e, s);
  }
  __syncthreads();

  // phase T: stable top-8 by selection (strict > keeps lowest index on ties)
  if (act) {
    const int tok = tokS;
    const float invv = inv_s[tok];
    const size_t tg = (size_t)(token0 + tok);
#pragma unroll 1
    for (int r = 0; r < 8; ++r) {
      float bv = -1.0f;
      int bi = 0;
      for (int e = 0; e < 64; ++e) {
        float p = lt[e * 68 + tok];
        if (p > bv) { bv = p; bi = e; }
      }
      lt[bi * 68 + tok] = -1.0f;
      atomicAdd(ce_lds + bi, 1.0f);
      out[tg * 8 + r] = (float)bi;
      out[(size_t)N * 8 + tg * 8 + r] = bv * invv;
    }
  }
  __syncthreads();
  if (tid < 64) atomicAdd(ce_g + tid, ce_lds[tid]);
}

// ---- w [64][4096] -> wT [4096][64] ----
__global__ void transpose_w(const float* __restrict__ w, float* __restrict__ wt) {
  __shared__ float t[32][33];
  const int k0 = blockIdx.x << 5;
  const int e0 = blockIdx.y << 5;
  const int tx = threadIdx.x;  // 0..31
  const int ty = threadIdx.y;  // 0..7
#pragma unroll
  for (int i = ty; i < 32; i += 8)
    t[i][tx] = w[(size_t)(e0 + i) * DDIM + k0 + tx];
  __syncthreads();
#pragma unroll
  for (int i = ty; i < 32; i += 8)
    wt[(size_t)(k0 + i) * EXPERTS + e0 + tx] = t[tx][i];
}

__global__ void aux_final(const float* __restrict__ pi_g,
                          const float* __restrict__ ce_g,
                          float* __restrict__ out_aux, int N) {
  const int e = threadIdx.x;  // 64
  float v = (pi_g[e] / (float)N) * (ce_g[e] / ((float)N * 8.0f)) * 64.0f * 0.01f;
#pragma unroll
  for (int off = 32; off; off >>= 1) v += __shfl_down(v, off, 64);
  if (e == 0) *out_aux = v;
}

extern "C" void kernel_launch(void* const* d_in, const int* in_sizes, int n_in,
                              void* d_out, int out_size, void* d_ws, size_t ws_size,
                              hipStream_t stream) {
  (void)n_in; (void)out_size; (void)ws_size;
  const float* x = (const float*)d_in[0];
  const float* w = (const float*)d_in[1];
  float* out = (float*)d_out;
  const int N = in_sizes[0] / DDIM;  // 16384

  float* wT = (float*)d_ws;                    // 4096*64 floats = 1 MiB
  float* pi_g = wT + (size_t)DDIM * EXPERTS;   // 64 floats
  float* ce_g = pi_g + 64;                     // 64 floats

  hipMemsetAsync(pi_g, 0, 128 * sizeof(float), stream);
  transpose_w<<<dim3(DDIM / 32, EXPERTS / 32), dim3(32, 8), 0, stream>>>(w, wT);
  moe_gate_main<<<N / TT, 256, 0, stream>>>(x, wT, out, pi_g, ce_g, N);
  aux_final<<<1, 64, 0, stream>>>(pi_g, ce_g, out + (size_t)N * 16, N);
}